// Round 6
// baseline (24.520 us; speedup 1.0000x reference)
//
#include <hip/hip_runtime.h>
#include <math.h>

// FFA forward: h[t] = lambda*h[t-1] + x[t], lambda[m,c] = exp(a_m + i b_c)
// Output = REAL PART of h[t], float32, shape (B,T,MEM,CTX).
//
// Fused single kernel. Block = (b, m-pair): 1024 threads = (s:64, m2:2, cp:8).
// Each thread owns TWO adjacent c (c-pair -> ILP=2, float2 stores, one x load
// feeds both states) and a half-chunk of KCH=32 timesteps.
//   A) per-thread: segment-local end states (zero init) -> LDS
//   B) 32 lanes: serial affine scan over 64 segment states per (m2,c),
//      seeded from the memory input -> incoming state per segment
//   C) per-thread: replay segment from exact incoming state, store
//      float2 {Re(c0),Re(c0+1)}.
// Wave at fixed t: 4 s-segments x (2m x 8cp x 8B) = 4 aligned 128 B lines
// per store instruction.
// XCD swizzle: 256 blocks = 8 XCDs x 32; XCD k owns batch b=k so x[b]
// (512 KB) stays L2-resident across both passes.

#define BB   8
#define TT   2048
#define MEMD 64
#define CTXD 16
#define KCH  32                 // per-thread segment length
#define NSEG (TT / KCH)         // 64 segments

__device__ __forceinline__ float2 cmul(float2 u, float2 v) {
    return make_float2(u.x * v.x - u.y * v.y, u.x * v.y + u.y * v.x);
}

__device__ __forceinline__ float clip_a(float a) {
    const float LIMIT = (float)(88.72283911167299 / 1024.0 - 0.01); // log(F32_MAX)/MAX_LEN - FUDGE
    return fminf(fmaxf(a, -LIMIT), -1e-8f);
}

__global__ __launch_bounds__(1024) void ffa_fused(
        const float* __restrict__ x,
        const float* __restrict__ mem_r,
        const float* __restrict__ mem_i,
        const float* __restrict__ a,
        const float* __restrict__ bfreq,
        float* __restrict__ out) {
    // S[m2][c][s], row stride NSEG+1: scan-phase reads (stride 130 dwords
    // between lanes -> 2-way bank aliasing = free).
    __shared__ float2 S[2][CTXD][NSEG + 1];

    // Bijective XCD-contiguous swizzle (256 = 8 * 32): XCD k gets logical
    // blocks k*32..k*32+31 = all 32 m-pairs of batch b=k.
    int bid = blockIdx.x;
    int L = (bid & 7) * 32 + (bid >> 3);
    int b = L >> 5;
    int m0 = (L & 31) * 2;

    int tid = threadIdx.x;
    int cp = tid & 7;            // c-pair index: c0 = 2*cp
    int m2 = (tid >> 3) & 1;
    int s  = tid >> 4;           // segment 0..63
    int m = m0 + m2;
    int c0 = cp * 2;

    float am = clip_a(a[m]);
    float bc0 = bfreq[c0];
    float bc1 = bfreq[c0 + 1];
    float ea = expf(am);
    float2 lam0 = make_float2(ea * cosf(bc0), ea * sinf(bc0));
    float2 lam1 = make_float2(ea * cosf(bc1), ea * sinf(bc1));

    const float* xp = x + ((size_t)(b * TT + s * KCH)) * MEMD + m;

    // Phase A: segment-local states, zero init. One x load feeds both c's.
    float2 h0 = make_float2(0.f, 0.f);
    float2 h1 = make_float2(0.f, 0.f);
#pragma unroll 8
    for (int t = 0; t < KCH; ++t) {
        float xv = xp[(size_t)t * MEMD];
        h0 = cmul(lam0, h0); h0.x += xv;
        h1 = cmul(lam1, h1); h1.x += xv;
    }
    S[m2][c0][s] = h0;
    S[m2][c0 + 1][s] = h1;
    __syncthreads();

    // Phase B: serial affine scan over segments, 32 lanes (one per (m2,c)).
    // In-place: S[m2][c][s] becomes the INCOMING state for segment s.
    if (tid < 32) {
        int cc = tid & (CTXD - 1);
        int lm2 = tid >> 4;
        int sm = m0 + lm2;
        float sam = clip_a(a[sm]);
        float sbc = bfreq[cc];
        float eaK = expf(sam * (float)KCH);
        float argK = sbc * (float)KCH;
        float2 lamK = make_float2(eaK * cosf(argK), eaK * sinf(argK));
        int seq = (b * MEMD + sm) * CTXD + cc;
        float2 hh = make_float2(mem_r[seq], mem_i[seq]);
#pragma unroll 8
        for (int ss = 0; ss < NSEG; ++ss) {
            float2 sv = S[lm2][cc][ss];
            S[lm2][cc][ss] = hh;
            hh = cmul(lamK, hh);
            hh.x += sv.x;
            hh.y += sv.y;
        }
    }
    __syncthreads();

    // Phase C: replay segment from exact incoming state; store real parts
    // of the c-pair as one float2 (8 B) per step.
    h0 = S[m2][c0][s];
    h1 = S[m2][c0 + 1][s];
    float* op = out + (((size_t)(b * TT + s * KCH)) * MEMD + m) * CTXD + c0;
#pragma unroll 8
    for (int t = 0; t < KCH; ++t) {
        float xv = xp[(size_t)t * MEMD];
        h0 = cmul(lam0, h0); h0.x += xv;
        h1 = cmul(lam1, h1); h1.x += xv;
        *reinterpret_cast<float2*>(op + (size_t)t * (MEMD * CTXD)) =
            make_float2(h0.x, h1.x);
    }
}

extern "C" void kernel_launch(void* const* d_in, const int* in_sizes, int n_in,
                              void* d_out, int out_size, void* d_ws, size_t ws_size,
                              hipStream_t stream) {
    const float* x     = (const float*)d_in[0];
    const float* mem_r = (const float*)d_in[1];
    const float* mem_i = (const float*)d_in[2];
    const float* a     = (const float*)d_in[3];
    const float* bfrq  = (const float*)d_in[4];
    float* out = (float*)d_out;

    ffa_fused<<<BB * (MEMD / 2), 1024, 0, stream>>>(x, mem_r, mem_i, a, bfrq, out);
}